// Round 10
// baseline (4252.040 us; speedup 1.0000x reference)
//
#include <hip/hip_runtime.h>

#define B 4
#define N 8192
#define F 64
#define S 2048
#define K 16
#define C 128
#define R (B*S*K)   // 131072 rows

// ---------- exact-arithmetic helpers (match numpy op order, no fma fusion) ----------
__device__ __forceinline__ float norm2f(float x, float y, float z) {
#pragma clang fp contract(off)
  return (x*x + y*y) + z*z;
}

__device__ __forceinline__ float dist2_sub(float ax, float ay, float az,
                                           float bx, float by, float bz) {
#pragma clang fp contract(off)
  float dx = ax - bx, dy = ay - by, dz = az - bz;
  return (dx*dx + dy*dy) + dz*dz;          // ((d0+d1)+d2), separate rounding
}

__device__ __forceinline__ float knn_d2(float4 q, float4 p) {
#pragma clang fp contract(off)
  float dot = (q.x*p.x + q.y*p.y) + q.z*p.z;
  return (q.w + p.w) - 2.0f*dot;           // (qn+pn) - 2*dot, reference order
}

// opaque def: forbids rematerialization of the value -> stays in a VGPR
__device__ __forceinline__ void pinf(float& v) { asm volatile("" : "+v"(v)); }

// ---------- DPP cross-lane (VALU pipe). bound_ctrl=1 -> invalid lanes read 0:
// identity-safe for f32-max of POSITIVE values and u32-max. HW-verified rounds 2-9.
#define DPP_F(v, ctrl) __int_as_float(__builtin_amdgcn_update_dpp(0, __float_as_int(v), ctrl, 0xf, 0xf, true))
#define DPP_U(v, ctrl) ((unsigned)__builtin_amdgcn_update_dpp(0, (int)(v), ctrl, 0xf, 0xf, true))
__device__ __forceinline__ unsigned umaxu(unsigned a, unsigned b) { return a > b ? a : b; }
__device__ __forceinline__ float rdlane_f(float v, int l) {
  return __int_as_float(__builtin_amdgcn_readlane(__float_as_int(v), l));
}

#define WAVE_MAX_F(x) do { \
  x = fmaxf(x, DPP_F(x,0x111)); x = fmaxf(x, DPP_F(x,0x112)); \
  x = fmaxf(x, DPP_F(x,0x114)); x = fmaxf(x, DPP_F(x,0x118)); \
  x = fmaxf(x, DPP_F(x,0x142)); x = fmaxf(x, DPP_F(x,0x143)); } while(0)

#define WAVE_MAX_U(x) do { \
  x = umaxu(x, DPP_U(x,0x111)); x = umaxu(x, DPP_U(x,0x112)); \
  x = umaxu(x, DPP_U(x,0x114)); x = umaxu(x, DPP_U(x,0x118)); \
  x = umaxu(x, DPP_U(x,0x142)); x = umaxu(x, DPP_U(x,0x143)); } while(0)

// 6-bit/axis Morton interleave (18 bits)
__device__ __forceinline__ unsigned mort6(int qx, int qy, int qz) {
  unsigned m = 0;
#pragma unroll
  for (int b = 0; b < 6; ++b) {
    m |= ((unsigned)((qx>>b)&1) << (3*b+2))
       | ((unsigned)((qy>>b)&1) << (3*b+1))
       | ((unsigned)((qz>>b)&1) << (3*b+0));
  }
  return m;
}

// ---------- prep: pad xyz to float4 with |p|^2 in w ----------
__global__ void prep_kernel(const float* __restrict__ xyz, float4* __restrict__ pts4) {
  int i = blockIdx.x*blockDim.x + threadIdx.x;   // B*N
  if (i >= B*N) return;
  float x = xyz[i*3+0], y = xyz[i*3+1], z = xyz[i*3+2];
  pts4[i] = make_float4(x, y, z, norm2f(x, y, z));
}

// ---------- transpose w1 [o][c] -> w1t [c][o] for contiguous scalar weight loads ----------
__global__ void transpose_w1_kernel(const float* __restrict__ w1, float* __restrict__ w1t) {
  int i = blockIdx.x*256 + threadIdx.x;    // C*C = 16384
  int o = i >> 7, c = i & 127;
  w1t[c*C + o] = w1[o*C + c];
}

// ---------- FPS: 256 threads (measured-best), EXACT chunk-lazy update.
// Wave owns 2048 Morton-sorted pts as 8 chunks x 256; one scalar sphere per chunk;
// per-lane per-chunk exact (max,key) caches; skipped chunks are provably identity.
// Selection bit-exact; ties -> lowest ORIGINAL index via complement keys. ----------
__global__ __launch_bounds__(256, 1) void fps_kernel(const float4* __restrict__ pts4,
                                                     float4* __restrict__ q4,
                                                     float* __restrict__ out_xyz) {
  const int b = blockIdx.x;
  const int t = threadIdx.x;               // 0..255
  const int lane = t & 63;
  const int wid = t >> 6;                  // 0..3
  const float4* pb = pts4 + b*N;

  __shared__ float cx[N], cy[N], cz[N];    // 96 KB coords by ORIGINAL index
  __shared__ unsigned skey[N];             // 32 KB (morton<<13 | idx) sort keys
  __shared__ float sq[3*S];                // 24 KB winner sequence
  __shared__ float    swv[2][4];
  __shared__ unsigned swk[2][4];

  // ---- stage coords to LDS + Morton keys ----
#pragma unroll
  for (int j = 0; j < 32; ++j) {
    int i = j*256 + t;
    float4 v = pb[i];                      // coalesced
    cx[i] = v.x; cy[i] = v.y; cz[i] = v.z;
    int qx = (int)((v.x + 6.0f) * (64.0f/12.0f));
    int qy = (int)((v.y + 6.0f) * (64.0f/12.0f));
    int qz = (int)((v.z + 6.0f) * (64.0f/12.0f));
    qx = min(max(qx,0),63); qy = min(max(qy,0),63); qz = min(max(qz,0),63);
    skey[i] = (mort6(qx,qy,qz) << 13) | (unsigned)i;
  }
  __syncthreads();

  // ---- in-LDS bitonic sort (round-6-verified; affects SPEED only) ----
  for (unsigned k = 2; k <= (unsigned)N; k <<= 1) {
    for (unsigned j = k >> 1; j > 0; j >>= 1) {
#pragma unroll
      for (int m = 0; m < 32; ++m) {
        int i = m*256 + t;
        int ixj = i ^ (int)j;
        if (ixj > i) {
          unsigned a = skey[i], c2 = skey[ixj];
          bool up = ((i & (int)k) == 0);
          if ((a > c2) == up) { skey[i] = c2; skey[ixj] = a; }
        }
      }
      __syncthreads();
    }
  }

  // ---- ownership: wave wid: chunks c=0..7 of 256 sorted pts; lane: 4 pts/chunk ----
  float px[32], py[32], pz[32], md[32]; unsigned okey[32];
#pragma unroll
  for (int c = 0; c < 8; ++c) {
#pragma unroll
    for (int k2 = 0; k2 < 4; ++k2) {
      int slot = c*4 + k2;
      int pos = wid*2048 + c*256 + lane*4 + k2;
      int oi = (int)(skey[pos] & 0x1FFFu);
      float x = cx[oi], y = cy[oi], z = cz[oi];
      pinf(x); pinf(y); pinf(z);
      px[slot] = x; py[slot] = y; pz[slot] = z;
      md[slot] = 1e10f;                    // BIG
      okey[slot] = 0x7FFFFFFFu - (unsigned)oi;   // max key == min orig idx
    }
  }

  // ---- per-chunk bounding spheres (lane c holds chunk c's sphere) ----
  float scx = 0.f, scy = 0.f, scz = 0.f, sr = 0.f;
#pragma unroll
  for (int c = 0; c < 8; ++c) {
    float pxp=-1e30f, pxm=-1e30f, pyp=-1e30f, pym=-1e30f, pzp=-1e30f, pzm=-1e30f;
#pragma unroll
    for (int k2 = 0; k2 < 4; ++k2) {
      int slot = c*4 + k2;
      pxp = fmaxf(pxp, px[slot]+16.f); pxm = fmaxf(pxm, 16.f-px[slot]);  // >0: DPP-safe
      pyp = fmaxf(pyp, py[slot]+16.f); pym = fmaxf(pym, 16.f-py[slot]);
      pzp = fmaxf(pzp, pz[slot]+16.f); pzm = fmaxf(pzm, 16.f-pz[slot]);
    }
    WAVE_MAX_F(pxp); WAVE_MAX_F(pxm);
    WAVE_MAX_F(pyp); WAVE_MAX_F(pym);
    WAVE_MAX_F(pzp); WAVE_MAX_F(pzm);
    float ccx = (rdlane_f(pxp,63) - rdlane_f(pxm,63)) * 0.5f;  // (maxx+minx)/2
    float ccy = (rdlane_f(pyp,63) - rdlane_f(pym,63)) * 0.5f;
    float ccz = (rdlane_f(pzp,63) - rdlane_f(pzm,63)) * 0.5f;
    float r2l = 0.f;
#pragma unroll
    for (int k2 = 0; k2 < 4; ++k2) {
      int slot = c*4 + k2;
      float dx = px[slot]-ccx, dy = py[slot]-ccy, dz = pz[slot]-ccz;
      r2l = fmaxf(r2l, dx*dx + dy*dy + dz*dz);
    }
    WAVE_MAX_F(r2l);
    float rc = sqrtf(rdlane_f(r2l,63)) * 1.0001f + 1e-9f;      // conservative
    bool me = (lane == c);
    scx = me ? ccx : scx; scy = me ? ccy : scy; scz = me ? ccz : scz;
    sr  = me ? rc  : sr;
  }
  __syncthreads();                         // skey reads done; sq writes follow

  // ---- serial FPS loop ----
  float cmax[8]; unsigned ckey[8];         // exact per-lane per-chunk caches
#pragma unroll
  for (int c = 0; c < 8; ++c) { cmax[c] = 0.f; ckey[c] = 0u; }
  float wx = cx[0], wy = cy[0], wz = cz[0];   // reference starts at idx 0
  float bm_s = 3.4e38f;                    // sqrt(block max md) upper bound

  for (int s = 0; ; ++s) {
    if (t == 0) { sq[s] = wx; sq[S+s] = wy; sq[2*S+s] = wz; }
    if (s == S-1) break;

    // chunk skip tests (lanes 0..7 evaluate the wave's 8 chunks in parallel)
    float dxc = scx - wx, dyc = scy - wy, dzc = scz - wz;
    float d2c = dxc*dxc + dyc*dyc + dzc*dzc;
    bool proc = (lane < 8) && (sqrtf(d2c)*0.9999f < sr + bm_s);
    unsigned mask = (unsigned)(__ballot(proc) & 0xFFull);   // wave-uniform

#pragma unroll
    for (int c = 0; c < 8; ++c) {
      if (mask & (1u<<c)) {                // scalar branch per chunk
        float cm = -1.0f; unsigned ck = 0u;
#pragma unroll
        for (int k2 = 0; k2 < 4; ++k2) {
          int slot = c*4 + k2;
          float d = dist2_sub(px[slot], py[slot], pz[slot], wx, wy, wz);
          float m = fminf(md[slot], d);
          md[slot] = m;
          bool g = (m > cm) || ((m == cm) & (okey[slot] > ck));
          cm = g ? m : cm;  ck = g ? okey[slot] : ck;
        }
        cmax[c] = cm; ckey[c] = ck;        // exact refresh
      }
    }
    // fold 8 exact pairs (skipped chunks: caches still exact since md unchanged)
    float bv = cmax[0]; unsigned bk = ckey[0];
#pragma unroll
    for (int c = 1; c < 8; ++c) {
      bool g = (cmax[c] > bv) || ((cmax[c] == bv) & (ckey[c] > bk));
      bv = g ? cmax[c] : bv;  bk = g ? ckey[c] : bk;
    }

    // verified two-chain wave reduce: exact max, then min-orig-idx key
    float rv = bv;
    WAVE_MAX_F(rv);
    float bwu = rdlane_f(rv, 63);
    unsigned ki = (bv == bwu) ? bk : 0u;
    WAVE_MAX_U(ki);

    int par = s & 1;
    if (lane == 63) { swv[par][wid] = rv; swk[par][wid] = ki; }
    __syncthreads();                       // parity dbuf -> single barrier/step

    float v0 = swv[par][0], v1 = swv[par][1], v2 = swv[par][2], v3 = swv[par][3];
    float bm = fmaxf(fmaxf(v0, v1), fmaxf(v2, v3));        // exact block max
    unsigned c0 = (v0 == bm) ? swk[par][0] : 0u;
    unsigned c1 = (v1 == bm) ? swk[par][1] : 0u;
    unsigned c2 = (v2 == bm) ? swk[par][2] : 0u;
    unsigned c3 = (v3 == bm) ? swk[par][3] : 0u;
    unsigned kb = umaxu(umaxu(c0, c1), umaxu(c2, c3));     // min orig idx at bm
    int w = (int)(0x7FFFFFFFu - kb);
    wx = cx[w]; wy = cy[w]; wz = cz[w];    // same-address LDS broadcast
    bm_s = sqrtf(bm) * 1.0001f;            // conservative bound for next step
  }

  __syncthreads();                         // seq complete
#pragma unroll
  for (int i = t; i < S; i += 256) {
    float x = sq[i], y = sq[S+i], z = sq[2*S+i];
    q4[b*S + i] = make_float4(x, y, z, norm2f(x, y, z));
    out_xyz[(b*S + i)*3 + 0] = x;
    out_xyz[(b*S + i)*3 + 1] = y;
    out_xyz[(b*S + i)*3 + 2] = z;
  }
}

// ---------- KNN: one WAVE per query; per-lane sorted top-16 over 128 points,
// then exact 16-round DPP extraction merge (min d, tie -> min point index) ----------
__global__ __launch_bounds__(256, 4) void knn_kernel(const float4* __restrict__ pts4,
                                                     const float4* __restrict__ q4,
                                                     int* __restrict__ knn) {
  const int gtid = blockIdx.x*256 + threadIdx.x;
  const int wave = gtid >> 6;              // query id, 0..B*S-1
  const int lane = threadIdx.x & 63;
  const int b = wave >> 11;                // S = 2048
  const float4* pb = pts4 + (size_t)b*N;
  float4 q = q4[wave];                     // same addr across wave -> broadcast

  float dv[16]; int di[16];
#pragma unroll
  for (int j = 0; j < 16; ++j) { dv[j] = 3.4e38f; di[j] = 0x7FFFFFFF; }

  for (int j = 0; j < N/64; ++j) {
    int n = j*64 + lane;
    float4 p = pb[n];                      // coalesced global_load_dwordx4
    float d2 = knn_d2(q, p);
#pragma unroll
    for (int k = 15; k >= 1; --k) {
      bool s1 = d2 < dv[k-1];              // strict: incumbent (earlier idx) wins ties
      bool s2 = d2 < dv[k];
      dv[k] = fmaxf(dv[k-1], fminf(d2, dv[k]));
      di[k] = s1 ? di[k-1] : (s2 ? n : di[k]);
    }
    bool s0 = d2 < dv[0];
    dv[0] = fminf(d2, dv[0]);
    di[0] = s0 ? n : di[0];
  }

  int myg = 0;
#pragma unroll 1
  for (int r = 0; r < 16; ++r) {
    unsigned bits = __float_as_uint(dv[0]);
    unsigned ord  = bits ^ (0x80000000u | (unsigned)(((int)bits) >> 31));
    unsigned mk   = ~ord;                  // max(mk) == min distance (total order)
    unsigned m = mk;
    WAVE_MAX_U(m);
    unsigned wm = (unsigned)__builtin_amdgcn_readlane((int)m, 63);
    unsigned ci = (mk == wm) ? ~(unsigned)di[0] : 0u;
    unsigned m2 = ci;
    WAVE_MAX_U(m2);
    unsigned wi = (unsigned)__builtin_amdgcn_readlane((int)m2, 63);
    int g = (int)~wi;                      // winning global point index
    if (lane == r) myg = g;
    bool win = (mk == wm) && ((unsigned)di[0] == ~wi);
#pragma unroll
    for (int k = 0; k < 15; ++k) {
      dv[k] = win ? dv[k+1] : dv[k];
      di[k] = win ? di[k+1] : di[k];
    }
    dv[15] = win ? 3.4e38f    : dv[15];
    di[15] = win ? 0x7FFFFFFF : di[15];
  }
  if (lane < 16) knn[wave*16 + lane] = myg;   // coalesced 16-wide store
}

// ---------- GEMM0: gather row (3 xyz-norm + 64 feat) and multiply by w0 [128x67] ----------
__global__ __launch_bounds__(256, 2) void gemm0_kernel(const float4* __restrict__ pts4,
                                                       const float4* __restrict__ q4,
                                                       const float* __restrict__ feat,
                                                       const int* __restrict__ knn,
                                                       const float* __restrict__ w0,
                                                       const float* __restrict__ b0,
                                                       float* __restrict__ Z) {
  int r = blockIdx.x*256 + threadIdx.x;    // 0..R-1
  int bs = r >> 4;                         // b*S + s
  int b  = r >> 15;                        // S*K = 32768 rows per batch
  int p  = knn[r];
  float4 q  = q4[bs];
  float4 pp = pts4[b*N + p];

  float row[67];
  row[0] = pp.x - q.x; row[1] = pp.y - q.y; row[2] = pp.z - q.z;
  const float4* fp = (const float4*)(feat + (size_t)(b*N + p)*F);
#pragma unroll
  for (int i = 0; i < 16; ++i) {
    float4 v = fp[i];
    row[3+4*i] = v.x; row[4+4*i] = v.y; row[5+4*i] = v.z; row[6+4*i] = v.w;
  }

  float* zr = Z + (size_t)r*C;
  for (int og = 0; og < C/4; ++og) {
    float a0 = b0[og*4+0], a1 = b0[og*4+1], a2 = b0[og*4+2], a3 = b0[og*4+3];
    const float* wr = w0 + og*4*67;        // uniform -> scalar loads
#pragma unroll
    for (int c = 0; c < 67; ++c) {
      float x = row[c];
      a0 = fmaf(x, wr[c      ], a0);
      a1 = fmaf(x, wr[67  + c], a1);
      a2 = fmaf(x, wr[134 + c], a2);
      a3 = fmaf(x, wr[201 + c], a3);
    }
    ((float4*)zr)[og] = make_float4(a0, a1, a2, a3);
  }
}

// ---------- per-channel stats partials: sum and sumsq over rows ----------
__global__ void stats_kernel(const float* __restrict__ Z, float* __restrict__ part) {
  int c = threadIdx.x & 127;
  int g = threadIdx.x >> 7;                // 0/1
  int chunk = blockIdx.x*2 + g;            // 0..255
  const int rows = R/256;                  // 512
  const float* zp = Z + (size_t)chunk*rows*C + c;
  float s1 = 0.f, s2 = 0.f;
  for (int j = 0; j < rows; ++j) {
    float v = zp[(size_t)j*C];
    s1 += v;
    s2 = fmaf(v, v, s2);
  }
  __shared__ float sh[2][2][128];
  sh[g][0][c] = s1; sh[g][1][c] = s2;
  __syncthreads();
  if (g == 0) {
    part[(blockIdx.x*128 + c)*2 + 0] = s1 + sh[1][0][c];
    part[(blockIdx.x*128 + c)*2 + 1] = s2 + sh[1][1][c];
  }
}

// ---------- finalize BN: A = gamma*rstd, B = beta - mean*gamma*rstd ----------
__global__ void finalize_kernel(const float* __restrict__ part,
                                const float* __restrict__ gamma,
                                const float* __restrict__ beta,
                                float* __restrict__ AB) {
  int c = threadIdx.x;                     // 128 threads
  float s1 = 0.f, s2 = 0.f;
  for (int i = 0; i < 128; ++i) {
    s1 += part[(i*128 + c)*2 + 0];
    s2 += part[(i*128 + c)*2 + 1];
  }
  const float inv = 1.0f/(float)R;
  float mean = s1*inv;
  float var  = s2*inv - mean*mean;         // biased variance
  float rstd = rsqrtf(var + 1e-5f);
  float a = gamma[c]*rstd;
  AB[c]     = a;
  AB[C + c] = beta[c] - mean*a;
}

// ---------- GEMM1: LDS-tiled (64 rows/block), no register spill, in-place on Z ----------
__global__ __launch_bounds__(256, 4) void gemm1_kernel(float* __restrict__ Z,
                                                       const float* __restrict__ AB0,
                                                       const float* __restrict__ w1t,
                                                       const float* __restrict__ b1) {
  __shared__ float hs[64 * 129];           // stride 129: 2-way bank aliasing = free
  const int tid = threadIdx.x;
  const size_t base = (size_t)blockIdx.x * 64;

  const float4* Z4 = (const float4*)(Z + base * C);
#pragma unroll
  for (int k = 0; k < 8; ++k) {
    int f = tid + k*256;                   // float4 index, 0..2047
    int row = f >> 5, c4 = f & 31;
    float4 v  = Z4[f];
    float4 A  = ((const float4*)AB0)[c4];
    float4 Bb = ((const float4*)AB0)[32 + c4];
    int lb = row*129 + c4*4;
    hs[lb+0] = fmaxf(fmaf(v.x, A.x, Bb.x), 0.f);
    hs[lb+1] = fmaxf(fmaf(v.y, A.y, Bb.y), 0.f);
    hs[lb+2] = fmaxf(fmaf(v.z, A.z, Bb.z), 0.f);
    hs[lb+3] = fmaxf(fmaf(v.w, A.w, Bb.w), 0.f);
  }
  __syncthreads();

  const int row = tid & 63;
  const int qu  = __builtin_amdgcn_readfirstlane(tid >> 6);  // wave-uniform -> s_loads
  const float* wq = w1t + qu*32;           // w1t[c*C + o]
  float acc[32];
#pragma unroll
  for (int o = 0; o < 32; ++o) acc[o] = b1[qu*32 + o];
  const float* hrow = hs + row*129;
  for (int c = 0; c < C; ++c) {
    float x = hrow[c];
    const float* wr = wq + c*C;            // uniform: s_load_dwordx16 x2
#pragma unroll
    for (int o = 0; o < 32; ++o) acc[o] = fmaf(x, wr[o], acc[o]);
  }
  __syncthreads();

#pragma unroll
  for (int o = 0; o < 32; ++o) hs[row*129 + qu*32 + o] = acc[o];
  __syncthreads();
  float4* Zo = (float4*)(Z + base * C);
#pragma unroll
  for (int k = 0; k < 8; ++k) {
    int f = tid + k*256;
    int row2 = f >> 5, c4 = f & 31;
    int lb = row2*129 + c4*4;
    Zo[f] = make_float4(hs[lb+0], hs[lb+1], hs[lb+2], hs[lb+3]);
  }
}

// ---------- maxpool over K with BN1+ReLU fused ----------
__global__ void maxpool_kernel(const float* __restrict__ Z,
                               const float* __restrict__ AB1,
                               float* __restrict__ outF) {
  int t = blockIdx.x*256 + threadIdx.x;    // B*S*32
  int bs = t >> 5, c4 = t & 31;
  const float4* zp = (const float4*)Z + (size_t)bs*K*(C/4) + c4;
  float4 A  = ((const float4*)AB1)[c4];
  float4 Bb = ((const float4*)(AB1 + C))[c4];
  float4 m = make_float4(-3.4e38f, -3.4e38f, -3.4e38f, -3.4e38f);
#pragma unroll
  for (int k = 0; k < K; ++k) {
    float4 z = zp[(size_t)k*(C/4)];
    m.x = fmaxf(m.x, fmaf(z.x, A.x, Bb.x));
    m.y = fmaxf(m.y, fmaf(z.y, A.y, Bb.y));
    m.z = fmaxf(m.z, fmaf(z.z, A.z, Bb.z));
    m.w = fmaxf(m.w, fmaf(z.w, A.w, Bb.w));
  }
  m.x = fmaxf(m.x, 0.f); m.y = fmaxf(m.y, 0.f);
  m.z = fmaxf(m.z, 0.f); m.w = fmaxf(m.w, 0.f);
  ((float4*)outF)[t] = m;                  // max(relu(x)) == relu(max(x))
}

extern "C" void kernel_launch(void* const* d_in, const int* in_sizes, int n_in,
                              void* d_out, int out_size, void* d_ws, size_t ws_size,
                              hipStream_t stream) {
  const float* xyz      = (const float*)d_in[0];
  const float* features = (const float*)d_in[1];
  const float* w0  = (const float*)d_in[2];
  const float* b0  = (const float*)d_in[3];
  const float* g0  = (const float*)d_in[4];
  const float* be0 = (const float*)d_in[5];
  const float* w1  = (const float*)d_in[6];
  const float* b1  = (const float*)d_in[7];
  const float* g1  = (const float*)d_in[8];
  const float* be1 = (const float*)d_in[9];

  char* wp = (char*)d_ws;
  float4* pts4 = (float4*)wp;  wp += (size_t)B*N*sizeof(float4);     // 512 KB
  float4* q4   = (float4*)wp;  wp += (size_t)B*S*sizeof(float4);     // 128 KB
  int*    knn  = (int*)wp;     wp += (size_t)R*sizeof(int);          // 512 KB
  float*  Z    = (float*)wp;   wp += (size_t)R*C*sizeof(float);      // 64 MB
  float*  part = (float*)wp;   wp += (size_t)128*C*2*sizeof(float);  // 128 KB
  float*  AB0  = (float*)wp;   wp += (size_t)2*C*sizeof(float);
  float*  AB1  = (float*)wp;   wp += (size_t)2*C*sizeof(float);
  float*  w1t  = (float*)wp;   wp += (size_t)C*C*sizeof(float);      // 64 KB

  float* out_xyz  = (float*)d_out;            // [B,S,3]
  float* out_feat = (float*)d_out + B*S*3;    // [B,S,C]

  prep_kernel<<<(B*N)/256, 256, 0, stream>>>(xyz, pts4);
  transpose_w1_kernel<<<(C*C)/256, 256, 0, stream>>>(w1, w1t);
  fps_kernel<<<B, 256, 0, stream>>>(pts4, q4, out_xyz);
  knn_kernel<<<(B*S*64)/256, 256, 0, stream>>>(pts4, q4, knn);
  gemm0_kernel<<<R/256, 256, 0, stream>>>(pts4, q4, features, knn, w0, b0, Z);
  stats_kernel<<<128, 256, 0, stream>>>(Z, part);
  finalize_kernel<<<1, 128, 0, stream>>>(part, g0, be0, AB0);
  gemm1_kernel<<<R/64, 256, 0, stream>>>(Z, AB0, w1t, b1);
  stats_kernel<<<128, 256, 0, stream>>>(Z, part);
  finalize_kernel<<<1, 128, 0, stream>>>(part, g1, be1, AB1);
  maxpool_kernel<<<(B*S*32)/256, 256, 0, stream>>>(Z, AB1, out_feat);
}

// Round 11
// 2329.103 us; speedup vs baseline: 1.8256x; 1.8256x over previous
//
#include <hip/hip_runtime.h>

#define B 4
#define N 8192
#define F 64
#define S 2048
#define K 16
#define C 128
#define R (B*S*K)   // 131072 rows

typedef float v2f __attribute__((ext_vector_type(2)));

// ---------- exact-arithmetic helpers (match numpy op order, no fma fusion) ----------
__device__ __forceinline__ float norm2f(float x, float y, float z) {
#pragma clang fp contract(off)
  return (x*x + y*y) + z*z;
}

__device__ __forceinline__ float knn_d2(float4 q, float4 p) {
#pragma clang fp contract(off)
  float dot = (q.x*p.x + q.y*p.y) + q.z*p.z;
  return (q.w + p.w) - 2.0f*dot;           // (qn+pn) - 2*dot, reference order
}

// opaque def: forbids rematerialization of the value -> stays in a VGPR
__device__ __forceinline__ void pinf(float& v) { asm volatile("" : "+v"(v)); }

// ---------- DPP cross-lane (VALU pipe). bound_ctrl=1 -> invalid lanes read 0:
// identity-safe for u32/u64 max of positive values. HW-verified rounds 2-10.
#define DPP_U(v, ctrl) ((unsigned)__builtin_amdgcn_update_dpp(0, (int)(v), ctrl, 0xf, 0xf, true))
__device__ __forceinline__ unsigned umaxu(unsigned a, unsigned b) { return a > b ? a : b; }

#define WAVE_MAX_U(x) do { \
  x = umaxu(x, DPP_U(x,0x111)); x = umaxu(x, DPP_U(x,0x112)); \
  x = umaxu(x, DPP_U(x,0x114)); x = umaxu(x, DPP_U(x,0x118)); \
  x = umaxu(x, DPP_U(x,0x142)); x = umaxu(x, DPP_U(x,0x143)); } while(0)

// u64 max across the wave: per stage, DPP both halves then 64-bit compare-select.
#define DPP_U64(v, ctrl) ( ((unsigned long long)DPP_U((unsigned)((v)>>32), ctrl) << 32) \
                         | (unsigned long long)DPP_U((unsigned)(v), ctrl) )
#define WAVE_MAX_U64(x) do { \
  unsigned long long o_; \
  o_ = DPP_U64(x,0x111); x = (o_ > x) ? o_ : x; \
  o_ = DPP_U64(x,0x112); x = (o_ > x) ? o_ : x; \
  o_ = DPP_U64(x,0x114); x = (o_ > x) ? o_ : x; \
  o_ = DPP_U64(x,0x118); x = (o_ > x) ? o_ : x; \
  o_ = DPP_U64(x,0x142); x = (o_ > x) ? o_ : x; \
  o_ = DPP_U64(x,0x143); x = (o_ > x) ? o_ : x; } while(0)

// ---------- prep: pad xyz to float4 with |p|^2 in w ----------
__global__ void prep_kernel(const float* __restrict__ xyz, float4* __restrict__ pts4) {
  int i = blockIdx.x*blockDim.x + threadIdx.x;   // B*N
  if (i >= B*N) return;
  float x = xyz[i*3+0], y = xyz[i*3+1], z = xyz[i*3+2];
  pts4[i] = make_float4(x, y, z, norm2f(x, y, z));
}

// ---------- transpose w1 [o][c] -> w1t [c][o] for contiguous scalar weight loads ----------
__global__ void transpose_w1_kernel(const float* __restrict__ w1, float* __restrict__ w1t) {
  int i = blockIdx.x*256 + threadIdx.x;    // C*C = 16384
  int o = i >> 7, c = i & 127;
  w1t[c*C + o] = w1[o*C + c];
}

// ---------- FPS: one block per batch, 256 threads (r7 verified structure).
// New reduction: single u64 lexicographic chain (md>=0 => float cmp == bit cmp),
// key packed as (step+1)<<45 | md_bits<<13 | (8191-oi); monotone step field =>
// ONE LDS atomicMax location, no reset, no tail tree, single barrier/step. ----------
__global__ __launch_bounds__(256, 1) void fps_kernel(const float4* __restrict__ pts4,
                                                     float4* __restrict__ q4,
                                                     float* __restrict__ out_xyz) {
  const int b = blockIdx.x;
  const int t = threadIdx.x;
  const float4* pb = pts4 + b*N;

  __shared__ float4 cw[N];                 // 128 KB point cache (winner lookup, b128 read)
  __shared__ float sqx[S], sqy[S], sqz[S]; // 24 KB winner sequence
  __shared__ unsigned long long redloc;    // single monotonic reduction cell

  // thread t owns points i*256+t, i=0..31, paired (2j, 2j+1); pinned in VGPRs
  v2f px[16], py[16], pz[16], md[16];
#pragma unroll
  for (int j = 0; j < 16; ++j) {
    int i0 = (2*j)*256 + t, i1 = (2*j+1)*256 + t;
    float4 v0 = pb[i0];                    // coalesced
    float4 v1 = pb[i1];
    cw[i0] = v0; cw[i1] = v1;
    pinf(v0.x); pinf(v0.y); pinf(v0.z);
    pinf(v1.x); pinf(v1.y); pinf(v1.z);
    px[j] = (v2f){v0.x, v1.x};
    py[j] = (v2f){v0.y, v1.y};
    pz[j] = (v2f){v0.z, v1.z};
    md[j] = (v2f){1e10f, 1e10f};           // BIG
  }
  if (t == 0) redloc = 0ull;
  __syncthreads();                         // redloc init + cw visible before use

  float wx, wy, wz;
  { float4 p0 = pb[0]; wx = p0.x; wy = p0.y; wz = p0.z; }  // reference starts at idx 0

  for (int s = 0; ; ++s) {
    if (t == 0) { sqx[s] = wx; sqy[s] = wy; sqz[s] = wz; }
    if (s == S-1) break;

    // packed min_d update + two independent argmax chains (slots 0..15 / 16..31).
    // per-element IEEE rounding identical to scalar ((dx*dx+dy*dy)+dz*dz).
    v2f wxx = (v2f){wx, wx}, wyy = (v2f){wy, wy}, wzz = (v2f){wz, wz};
    float bvA = -1.0f, bvB = -1.0f; int biA = 0, biB = 0;
#pragma unroll
    for (int j = 0; j < 16; ++j) {
#pragma clang fp contract(off)
      v2f dx = px[j] - wxx;
      v2f dy = py[j] - wyy;
      v2f dz = pz[j] - wzz;
      v2f d  = (dx*dx + dy*dy) + dz*dz;    // v_pk/scalar sub-mul-add, no fma
      v2f m;
      m.x = fminf(md[j].x, d.x);
      m.y = fminf(md[j].y, d.y);
      md[j] = m;
      if (j < 8) {                         // chain A: slots 0..15
        bool g0 = m.x > bvA;  bvA = g0 ? m.x : bvA;  biA = g0 ? (2*j)   : biA;
        bool g1 = m.y > bvA;  bvA = g1 ? m.y : bvA;  biA = g1 ? (2*j+1) : biA;
      } else {                             // chain B: slots 16..31
        bool g0 = m.x > bvB;  bvB = g0 ? m.x : bvB;  biB = g0 ? (2*j)   : biB;
        bool g1 = m.y > bvB;  bvB = g1 ? m.y : bvB;  biB = g1 ? (2*j+1) : biB;
      }
    }
    // merge chains: strict > keeps A (lower slots = lower global idx) on ties
    bool gB = bvB > bvA;
    float bv = gB ? bvB : bvA;             // bv >= 0 always (set at j=0 / j=8)
    int   bi = gB ? biB : biA;

    // pack: (s+1)<<45 | bv_bits<<13 | (8191 - oi); oi = bi*256 + t (13 bits).
    // max == (max bv, tie -> min original index); step field makes it monotone.
    unsigned key = 8191u - (((unsigned)bi << 8) + (unsigned)t);
    unsigned long long pk = ((unsigned long long)(unsigned)(s+1) << 45)
                          | ((unsigned long long)__float_as_uint(bv) << 13)
                          | (unsigned long long)key;
    WAVE_MAX_U64(pk);                      // lane 63 holds wave max
    if ((t & 63) == 63) atomicMax(&redloc, pk);   // ds_max_u64, 4 waves -> 1 cell
    __syncthreads();                       // all atomics visible; single barrier/step

    unsigned long long rw = redloc;        // same-address broadcast read
    int w = 8191 - (int)((unsigned)rw & 0x1FFFu); // winner original index
    float4 pw = cw[w];                     // one same-address ds_read_b128 broadcast
    wx = pw.x; wy = pw.y; wz = pw.z;
  }

  __syncthreads();                         // seq complete
#pragma unroll
  for (int i = t; i < S; i += 256) {
    float x = sqx[i], y = sqy[i], z = sqz[i];
    q4[b*S + i] = make_float4(x, y, z, norm2f(x, y, z));
    out_xyz[(b*S + i)*3 + 0] = x;
    out_xyz[(b*S + i)*3 + 1] = y;
    out_xyz[(b*S + i)*3 + 2] = z;
  }
}

// ---------- KNN: one WAVE per query; per-lane sorted top-16 over 128 points,
// then exact 16-round DPP extraction merge (min d, tie -> min point index) ----------
__global__ __launch_bounds__(256, 4) void knn_kernel(const float4* __restrict__ pts4,
                                                     const float4* __restrict__ q4,
                                                     int* __restrict__ knn) {
  const int gtid = blockIdx.x*256 + threadIdx.x;
  const int wave = gtid >> 6;              // query id, 0..B*S-1
  const int lane = threadIdx.x & 63;
  const int b = wave >> 11;                // S = 2048
  const float4* pb = pts4 + (size_t)b*N;
  float4 q = q4[wave];                     // same addr across wave -> broadcast

  float dv[16]; int di[16];
#pragma unroll
  for (int j = 0; j < 16; ++j) { dv[j] = 3.4e38f; di[j] = 0x7FFFFFFF; }

  // scan: lane owns points n = j*64 + lane (ascending -> within-lane ties keep lower idx)
  for (int j = 0; j < N/64; ++j) {
    int n = j*64 + lane;
    float4 p = pb[n];                      // coalesced global_load_dwordx4
    float d2 = knn_d2(q, p);
#pragma unroll
    for (int k = 15; k >= 1; --k) {
      bool s1 = d2 < dv[k-1];              // strict: incumbent (earlier idx) wins ties
      bool s2 = d2 < dv[k];
      dv[k] = fmaxf(dv[k-1], fminf(d2, dv[k]));   // med3: sorted-insert value update
      di[k] = s1 ? di[k-1] : (s2 ? n : di[k]);
    }
    bool s0 = d2 < dv[0];
    dv[0] = fminf(d2, dv[0]);
    di[0] = s0 ? n : di[0];
  }

  // merge: 16 extraction rounds over the 64 sorted lane-lists
  int myg = 0;
#pragma unroll 1
  for (int r = 0; r < 16; ++r) {
    unsigned bits = __float_as_uint(dv[0]);
    unsigned ord  = bits ^ (0x80000000u | (unsigned)(((int)bits) >> 31));
    unsigned mk   = ~ord;                  // max(mk) == min distance (total order)
    unsigned m = mk;
    WAVE_MAX_U(m);
    unsigned wm = (unsigned)__builtin_amdgcn_readlane((int)m, 63);
    unsigned ci = (mk == wm) ? ~(unsigned)di[0] : 0u;
    unsigned m2 = ci;
    WAVE_MAX_U(m2);
    unsigned wi = (unsigned)__builtin_amdgcn_readlane((int)m2, 63);
    int g = (int)~wi;                      // winning global point index
    if (lane == r) myg = g;
    bool win = (mk == wm) && ((unsigned)di[0] == ~wi);
#pragma unroll
    for (int k = 0; k < 15; ++k) {
      dv[k] = win ? dv[k+1] : dv[k];
      di[k] = win ? di[k+1] : di[k];
    }
    dv[15] = win ? 3.4e38f    : dv[15];
    di[15] = win ? 0x7FFFFFFF : di[15];
  }
  if (lane < 16) knn[wave*16 + lane] = myg;   // coalesced 16-wide store
}

// ---------- GEMM0: gather row (3 xyz-norm + 64 feat) and multiply by w0 [128x67] ----------
__global__ __launch_bounds__(256, 2) void gemm0_kernel(const float4* __restrict__ pts4,
                                                       const float4* __restrict__ q4,
                                                       const float* __restrict__ feat,
                                                       const int* __restrict__ knn,
                                                       const float* __restrict__ w0,
                                                       const float* __restrict__ b0,
                                                       float* __restrict__ Z) {
  int r = blockIdx.x*256 + threadIdx.x;    // 0..R-1
  int bs = r >> 4;                         // b*S + s
  int b  = r >> 15;                        // S*K = 32768 rows per batch
  int p  = knn[r];
  float4 q  = q4[bs];
  float4 pp = pts4[b*N + p];

  float row[67];
  row[0] = pp.x - q.x; row[1] = pp.y - q.y; row[2] = pp.z - q.z;
  const float4* fp = (const float4*)(feat + (size_t)(b*N + p)*F);
#pragma unroll
  for (int i = 0; i < 16; ++i) {
    float4 v = fp[i];
    row[3+4*i] = v.x; row[4+4*i] = v.y; row[5+4*i] = v.z; row[6+4*i] = v.w;
  }

  float* zr = Z + (size_t)r*C;
  for (int og = 0; og < C/4; ++og) {
    float a0 = b0[og*4+0], a1 = b0[og*4+1], a2 = b0[og*4+2], a3 = b0[og*4+3];
    const float* wr = w0 + og*4*67;        // uniform -> scalar loads
#pragma unroll
    for (int c = 0; c < 67; ++c) {
      float x = row[c];
      a0 = fmaf(x, wr[c      ], a0);
      a1 = fmaf(x, wr[67  + c], a1);
      a2 = fmaf(x, wr[134 + c], a2);
      a3 = fmaf(x, wr[201 + c], a3);
    }
    ((float4*)zr)[og] = make_float4(a0, a1, a2, a3);
  }
}

// ---------- per-channel stats partials: sum and sumsq over rows ----------
__global__ void stats_kernel(const float* __restrict__ Z, float* __restrict__ part) {
  int c = threadIdx.x & 127;
  int g = threadIdx.x >> 7;                // 0/1
  int chunk = blockIdx.x*2 + g;            // 0..255
  const int rows = R/256;                  // 512
  const float* zp = Z + (size_t)chunk*rows*C + c;
  float s1 = 0.f, s2 = 0.f;
  for (int j = 0; j < rows; ++j) {
    float v = zp[(size_t)j*C];
    s1 += v;
    s2 = fmaf(v, v, s2);
  }
  __shared__ float sh[2][2][128];
  sh[g][0][c] = s1; sh[g][1][c] = s2;
  __syncthreads();
  if (g == 0) {
    part[(blockIdx.x*128 + c)*2 + 0] = s1 + sh[1][0][c];
    part[(blockIdx.x*128 + c)*2 + 1] = s2 + sh[1][1][c];
  }
}

// ---------- finalize BN: A = gamma*rstd, B = beta - mean*gamma*rstd ----------
__global__ void finalize_kernel(const float* __restrict__ part,
                                const float* __restrict__ gamma,
                                const float* __restrict__ beta,
                                float* __restrict__ AB) {
  int c = threadIdx.x;                     // 128 threads
  float s1 = 0.f, s2 = 0.f;
  for (int i = 0; i < 128; ++i) {
    s1 += part[(i*128 + c)*2 + 0];
    s2 += part[(i*128 + c)*2 + 1];
  }
  const float inv = 1.0f/(float)R;
  float mean = s1*inv;
  float var  = s2*inv - mean*mean;         // biased variance
  float rstd = rsqrtf(var + 1e-5f);
  float a = gamma[c]*rstd;
  AB[c]     = a;
  AB[C + c] = beta[c] - mean*a;
}

// ---------- GEMM1: LDS-tiled (64 rows/block), no register spill, in-place on Z ----------
__global__ __launch_bounds__(256, 4) void gemm1_kernel(float* __restrict__ Z,
                                                       const float* __restrict__ AB0,
                                                       const float* __restrict__ w1t,
                                                       const float* __restrict__ b1) {
  __shared__ float hs[64 * 129];           // stride 129: 2-way bank aliasing = free
  const int tid = threadIdx.x;
  const size_t base = (size_t)blockIdx.x * 64;

  const float4* Z4 = (const float4*)(Z + base * C);
#pragma unroll
  for (int k = 0; k < 8; ++k) {
    int f = tid + k*256;                   // float4 index, 0..2047
    int row = f >> 5, c4 = f & 31;
    float4 v  = Z4[f];
    float4 A  = ((const float4*)AB0)[c4];
    float4 Bb = ((const float4*)AB0)[32 + c4];
    int lb = row*129 + c4*4;
    hs[lb+0] = fmaxf(fmaf(v.x, A.x, Bb.x), 0.f);
    hs[lb+1] = fmaxf(fmaf(v.y, A.y, Bb.y), 0.f);
    hs[lb+2] = fmaxf(fmaf(v.z, A.z, Bb.z), 0.f);
    hs[lb+3] = fmaxf(fmaf(v.w, A.w, Bb.w), 0.f);
  }
  __syncthreads();

  const int row = tid & 63;
  const int qu  = __builtin_amdgcn_readfirstlane(tid >> 6);  // wave-uniform -> s_loads
  const float* wq = w1t + qu*32;           // w1t[c*C + o]
  float acc[32];
#pragma unroll
  for (int o = 0; o < 32; ++o) acc[o] = b1[qu*32 + o];
  const float* hrow = hs + row*129;
  for (int c = 0; c < C; ++c) {
    float x = hrow[c];
    const float* wr = wq + c*C;            // uniform: s_load_dwordx16 x2
#pragma unroll
    for (int o = 0; o < 32; ++o) acc[o] = fmaf(x, wr[o], acc[o]);
  }
  __syncthreads();

#pragma unroll
  for (int o = 0; o < 32; ++o) hs[row*129 + qu*32 + o] = acc[o];
  __syncthreads();
  float4* Zo = (float4*)(Z + base * C);
#pragma unroll
  for (int k = 0; k < 8; ++k) {
    int f = tid + k*256;
    int row2 = f >> 5, c4 = f & 31;
    int lb = row2*129 + c4*4;
    Zo[f] = make_float4(hs[lb+0], hs[lb+1], hs[lb+2], hs[lb+3]);
  }
}

// ---------- maxpool over K with BN1+ReLU fused ----------
__global__ void maxpool_kernel(const float* __restrict__ Z,
                               const float* __restrict__ AB1,
                               float* __restrict__ outF) {
  int t = blockIdx.x*256 + threadIdx.x;    // B*S*32
  int bs = t >> 5, c4 = t & 31;
  const float4* zp = (const float4*)Z + (size_t)bs*K*(C/4) + c4;
  float4 A  = ((const float4*)AB1)[c4];
  float4 Bb = ((const float4*)(AB1 + C))[c4];
  float4 m = make_float4(-3.4e38f, -3.4e38f, -3.4e38f, -3.4e38f);
#pragma unroll
  for (int k = 0; k < K; ++k) {
    float4 z = zp[(size_t)k*(C/4)];
    m.x = fmaxf(m.x, fmaf(z.x, A.x, Bb.x));
    m.y = fmaxf(m.y, fmaf(z.y, A.y, Bb.y));
    m.z = fmaxf(m.z, fmaf(z.z, A.z, Bb.z));
    m.w = fmaxf(m.w, fmaf(z.w, A.w, Bb.w));
  }
  m.x = fmaxf(m.x, 0.f); m.y = fmaxf(m.y, 0.f);
  m.z = fmaxf(m.z, 0.f); m.w = fmaxf(m.w, 0.f);
  ((float4*)outF)[t] = m;                  // max(relu(x)) == relu(max(x))
}

extern "C" void kernel_launch(void* const* d_in, const int* in_sizes, int n_in,
                              void* d_out, int out_size, void* d_ws, size_t ws_size,
                              hipStream_t stream) {
  const float* xyz      = (const float*)d_in[0];
  const float* features = (const float*)d_in[1];
  const float* w0  = (const float*)d_in[2];
  const float* b0  = (const float*)d_in[3];
  const float* g0  = (const float*)d_in[4];
  const float* be0 = (const float*)d_in[5];
  const float* w1  = (const float*)d_in[6];
  const float* b1  = (const float*)d_in[7];
  const float* g1  = (const float*)d_in[8];
  const float* be1 = (const float*)d_in[9];

  char* wp = (char*)d_ws;
  float4* pts4 = (float4*)wp;  wp += (size_t)B*N*sizeof(float4);     // 512 KB
  float4* q4   = (float4*)wp;  wp += (size_t)B*S*sizeof(float4);     // 128 KB
  int*    knn  = (int*)wp;     wp += (size_t)R*sizeof(int);          // 512 KB
  float*  Z    = (float*)wp;   wp += (size_t)R*C*sizeof(float);      // 64 MB
  float*  part = (float*)wp;   wp += (size_t)128*C*2*sizeof(float);  // 128 KB
  float*  AB0  = (float*)wp;   wp += (size_t)2*C*sizeof(float);
  float*  AB1  = (float*)wp;   wp += (size_t)2*C*sizeof(float);
  float*  w1t  = (float*)wp;   wp += (size_t)C*C*sizeof(float);      // 64 KB

  float* out_xyz  = (float*)d_out;            // [B,S,3]
  float* out_feat = (float*)d_out + B*S*3;    // [B,S,C]

  prep_kernel<<<(B*N)/256, 256, 0, stream>>>(xyz, pts4);
  transpose_w1_kernel<<<(C*C)/256, 256, 0, stream>>>(w1, w1t);
  fps_kernel<<<B, 256, 0, stream>>>(pts4, q4, out_xyz);
  knn_kernel<<<(B*S*64)/256, 256, 0, stream>>>(pts4, q4, knn);
  gemm0_kernel<<<R/256, 256, 0, stream>>>(pts4, q4, features, knn, w0, b0, Z);
  stats_kernel<<<128, 256, 0, stream>>>(Z, part);
  finalize_kernel<<<1, 128, 0, stream>>>(part, g0, be0, AB0);
  gemm1_kernel<<<R/64, 256, 0, stream>>>(Z, AB0, w1t, b1);
  stats_kernel<<<128, 256, 0, stream>>>(Z, part);
  finalize_kernel<<<1, 128, 0, stream>>>(part, g1, be1, AB1);
  maxpool_kernel<<<(B*S*32)/256, 256, 0, stream>>>(Z, AB1, out_feat);
}